// Round 2
// baseline (4673.429 us; speedup 1.0000x reference)
//
#include <hip/hip_runtime.h>

typedef float f32x4 __attribute__((ext_vector_type(4)));
typedef short bf16x8 __attribute__((ext_vector_type(8)));

#define TT    2048
#define DDIM  128
#define G3    384
#define NBBLK 16                                  // batch blocks of 16 rows
#define GXSTEP (24 * 256)                         // gx elements per t per batch-block
#define GX_BYTES ((size_t)NBBLK * TT * GXSTEP * 2)  // 402,653,184 B

__device__ __forceinline__ unsigned f2bf_u(float f) {
    unsigned u = __float_as_uint(f);
    return (u + 0x7FFFu + ((u >> 16) & 1u)) >> 16;   // RNE f32->bf16
}
__device__ __forceinline__ float bf_lo(unsigned u) { return __uint_as_float(u << 16); }
__device__ __forceinline__ float bf_hi(unsigned u) { return __uint_as_float(u & 0xffff0000u); }
__device__ __forceinline__ float sigm(float v)  { return 1.0f / (1.0f + __expf(-v)); }
__device__ __forceinline__ float tanh_(float v) { return 1.0f - 2.0f / (1.0f + __expf(2.0f * v)); }

// ---------------------------------------------------------------------------
// Kernel 1: gx[b,t,:] = x[b,:,t] @ W + b   (bf16 MFMA, full chip)
// Output layout (bf16): [bblk(16)][t(2048)][tile(24)][col(16)][row(16)]
//   = exactly the 16x16x32 MFMA C-fragment order the recurrent kernel consumes.
// grid (16 bblk, 16 ttile), block 256 (4 waves), each block does 128 t.
// ---------------------------------------------------------------------------
__global__ __launch_bounds__(256) void gx_gemm(
    const float* __restrict__ x, const float* __restrict__ W,
    const float* __restrict__ bias, unsigned short* __restrict__ gx)
{
    const int bblk  = blockIdx.x;
    const int ttile = blockIdx.y;
    const int tid = threadIdx.x;
    const int w  = tid >> 6;
    const int l  = tid & 63;
    const int lc = l & 15;     // A-row / B-col / C-col lane index
    const int lk = l >> 4;     // k-group

    __shared__ unsigned short xs[16 * 16 * DDIM];   // [t16][r16][d128] bf16, 64 KB, XOR-swizzled

    const int tiles[6] = {2*w, 2*w+1, 2*w+8, 2*w+9, 2*w+16, 2*w+17};

    // W fragments (B operand) in registers: 6 tiles x 4 ktiles
    bf16x8 wfrag[6][4];
    f32x4  binit[6];
    #pragma unroll
    for (int i6 = 0; i6 < 6; ++i6) {
        const int c = tiles[i6] * 16 + lc;
        const float bv = bias[c];
        binit[i6] = (f32x4){bv, bv, bv, bv};
        #pragma unroll
        for (int kt = 0; kt < 4; ++kt) {
            bf16x8 f;
            #pragma unroll
            for (int jj = 0; jj < 8; ++jj) {
                const int k = kt * 32 + lk * 8 + jj;
                f[jj] = (short)f2bf_u(W[k * G3 + c]);
            }
            wfrag[i6][kt] = f;
        }
    }

    // lane-constant swizzled LDS offsets for A-fragment reads
    int inoff[4];
    #pragma unroll
    for (int kt = 0; kt < 4; ++kt)
        inoff[kt] = (lc * 256 + kt * 64 + lk * 16) ^ ((lc & 7) << 4);

    const float* xb = x + (size_t)bblk * 16 * DDIM * TT;
    const int t0blk = ttile * 128;
    const int tq = tid & 3;          // which 4-t quarter this thread stages
    const int pbase = tid >> 2;      // (r,d) pair base

    for (int chunk = 0; chunk < 8; ++chunk) {
        __syncthreads();             // protect xs from previous chunk's readers
        const int t0 = t0blk + chunk * 16 + tq * 4;
        #pragma unroll 4
        for (int pp = 0; pp < 32; ++pp) {
            const int p = pbase + pp * 64;       // 0..2047
            const int r = p >> 7, d = p & 127;
            f32x4 v = *(const f32x4*)(xb + (size_t)p * TT + t0);
            const int base = ((r * 128 + d) * 2) ^ ((r & 7) << 4);
            #pragma unroll
            for (int j = 0; j < 4; ++j) {
                const int tloc = tq * 4 + j;
                xs[(tloc * 4096 + base) >> 1] = (unsigned short)f2bf_u(v[j]);
            }
        }
        __syncthreads();

        for (int t = 0; t < 16; ++t) {
            bf16x8 a[4];
            #pragma unroll
            for (int kt = 0; kt < 4; ++kt)
                a[kt] = *(const bf16x8*)((const char*)xs + t * 4096 + inoff[kt]);

            const int tglob = t0blk + chunk * 16 + t;
            #pragma unroll
            for (int i6 = 0; i6 < 6; ++i6) {
                f32x4 acc = binit[i6];
                #pragma unroll
                for (int kt = 0; kt < 4; ++kt)
                    acc = __builtin_amdgcn_mfma_f32_16x16x32_bf16(a[kt], wfrag[i6][kt], acc, 0, 0, 0);
                // pack 4 f32 -> 4 bf16 -> 8B store in C-frag order
                unsigned p0 = f2bf_u(acc[0]) | (f2bf_u(acc[1]) << 16);
                unsigned p1 = f2bf_u(acc[2]) | (f2bf_u(acc[3]) << 16);
                const size_t off = (((size_t)bblk * TT + tglob) * 24 + tiles[i6]) * 256
                                   + lc * 16 + lk * 4;
                *(uint2*)(gx + off) = make_uint2(p0, p1);
            }
        }
    }
}

// ---------------------------------------------------------------------------
// Kernel 2: sequential GRU recurrence. 16 blocks x 512 threads (8 waves).
// Wave w owns gate-triple w: tiles {w, w+8, w+16} (z, r, n) = D-cols [16w,16w+16).
// U fragments live in registers; h exchanged via 8 KB double-buffered LDS in
// A-fragment order (lane-linear ds_read_b128, conflict-free).
// ---------------------------------------------------------------------------
__global__ __launch_bounds__(512) void gru_rec(
    const unsigned short* __restrict__ gx, const float* __restrict__ U,
    float* __restrict__ out)
{
    const int bblk = blockIdx.x;
    const int tid = threadIdx.x;
    const int w  = tid >> 6;
    const int l  = tid & 63;
    const int lc = l & 15, lk = l >> 4;
    const int c  = w * 16 + lc;          // this lane's D-column

    // U fragments (B operand): z, r, n tiles x 4 ktiles
    bf16x8 uz[4], ur[4], un[4];
    #pragma unroll
    for (int kt = 0; kt < 4; ++kt) {
        bf16x8 fz, fr, fn;
        #pragma unroll
        for (int jj = 0; jj < 8; ++jj) {
            const int k = kt * 32 + lk * 8 + jj;
            fz[jj] = (short)f2bf_u(U[k * G3 + (w      * 16 + lc)]);
            fr[jj] = (short)f2bf_u(U[k * G3 + ((w+8)  * 16 + lc)]);
            fn[jj] = (short)f2bf_u(U[k * G3 + ((w+16) * 16 + lc)]);
        }
        uz[kt] = fz; ur[kt] = fr; un[kt] = fn;
    }

    __shared__ unsigned short hsA[2 * 4 * 64 * 8];   // [buf][kt][lane][jj] bf16, 8 KB

    for (int i = tid; i < 2 * 4 * 64 * 8; i += 512) hsA[i] = 0;

    float hold0 = 0.f, hold1 = 0.f, hold2 = 0.f, hold3 = 0.f;

    // h_new -> hsA write address: element (r = lk*4+i, c): kt=c>>5, lam=r+16*((c&31)>>3), jj=c&7
    const int wbase = (c >> 5) * 1024 + (lk * 4 + 16 * ((c & 31) >> 3)) * 16 + (c & 7) * 2;

    const unsigned short* gz = gx + ((size_t)bblk * TT * 24 + (w     )) * 256 + lc * 16 + lk * 4;
    const unsigned short* gr = gx + ((size_t)bblk * TT * 24 + (w + 8 )) * 256 + lc * 16 + lk * 4;
    const unsigned short* gn = gx + ((size_t)bblk * TT * 24 + (w + 16)) * 256 + lc * 16 + lk * 4;

    float* ob = out + ((size_t)(bblk * 16 + lk * 4) * DDIM + c) * TT;

    __syncthreads();

    // depth-4 gx prefetch (register ring, statically unrolled)
    uint2 PZ0 = *(const uint2*)(gz);              uint2 PR0 = *(const uint2*)(gr);              uint2 PN0 = *(const uint2*)(gn);
    uint2 PZ1 = *(const uint2*)(gz + GXSTEP);     uint2 PR1 = *(const uint2*)(gr + GXSTEP);     uint2 PN1 = *(const uint2*)(gn + GXSTEP);
    uint2 PZ2 = *(const uint2*)(gz + 2*GXSTEP);   uint2 PR2 = *(const uint2*)(gr + 2*GXSTEP);   uint2 PN2 = *(const uint2*)(gn + 2*GXSTEP);
    uint2 PZ3 = *(const uint2*)(gz + 3*GXSTEP);   uint2 PR3 = *(const uint2*)(gr + 3*GXSTEP);   uint2 PN3 = *(const uint2*)(gn + 3*GXSTEP);
    gz += 4 * GXSTEP; gr += 4 * GXSTEP; gn += 4 * GXSTEP;

    auto substep = [&](int t, int cur, uint2& pz, uint2& pr, uint2& pn,
                       bool dopf, int koff) {
        // unpack gx (consume prefetch regs)
        f32x4 az, ar;
        az[0] = bf_lo(pz.x); az[1] = bf_hi(pz.x); az[2] = bf_lo(pz.y); az[3] = bf_hi(pz.y);
        ar[0] = bf_lo(pr.x); ar[1] = bf_hi(pr.x); ar[2] = bf_lo(pr.y); ar[3] = bf_hi(pr.y);
        float g0 = bf_lo(pn.x), g1 = bf_hi(pn.x), g2 = bf_lo(pn.y), g3 = bf_hi(pn.y);
        // reissue prefetch for t+4 into the just-freed regs
        if (dopf) {
            pz = *(const uint2*)(gz + koff);
            pr = *(const uint2*)(gr + koff);
            pn = *(const uint2*)(gn + koff);
        }
        // h fragments (A operand), lane-linear -> conflict-free b128
        const char* hb = (const char*)hsA + cur * 4096 + l * 16;
        bf16x8 a0 = *(const bf16x8*)(hb);
        bf16x8 a1 = *(const bf16x8*)(hb + 1024);
        bf16x8 a2 = *(const bf16x8*)(hb + 2048);
        bf16x8 a3 = *(const bf16x8*)(hb + 3072);

        f32x4 an = (f32x4){0.f, 0.f, 0.f, 0.f};
        az = __builtin_amdgcn_mfma_f32_16x16x32_bf16(a0, uz[0], az, 0, 0, 0);
        ar = __builtin_amdgcn_mfma_f32_16x16x32_bf16(a0, ur[0], ar, 0, 0, 0);
        an = __builtin_amdgcn_mfma_f32_16x16x32_bf16(a0, un[0], an, 0, 0, 0);
        az = __builtin_amdgcn_mfma_f32_16x16x32_bf16(a1, uz[1], az, 0, 0, 0);
        ar = __builtin_amdgcn_mfma_f32_16x16x32_bf16(a1, ur[1], ar, 0, 0, 0);
        an = __builtin_amdgcn_mfma_f32_16x16x32_bf16(a1, un[1], an, 0, 0, 0);
        az = __builtin_amdgcn_mfma_f32_16x16x32_bf16(a2, uz[2], az, 0, 0, 0);
        ar = __builtin_amdgcn_mfma_f32_16x16x32_bf16(a2, ur[2], ar, 0, 0, 0);
        an = __builtin_amdgcn_mfma_f32_16x16x32_bf16(a2, un[2], an, 0, 0, 0);
        az = __builtin_amdgcn_mfma_f32_16x16x32_bf16(a3, uz[3], az, 0, 0, 0);
        ar = __builtin_amdgcn_mfma_f32_16x16x32_bf16(a3, ur[3], ar, 0, 0, 0);
        an = __builtin_amdgcn_mfma_f32_16x16x32_bf16(a3, un[3], an, 0, 0, 0);

        unsigned short* hw = hsA + (((cur ^ 1) * 4096 + wbase) >> 1);
        float gn4[4] = {g0, g1, g2, g3};
        float* hold[4] = {&hold0, &hold1, &hold2, &hold3};
        #pragma unroll
        for (int i = 0; i < 4; ++i) {
            const float zz = sigm(az[i]);
            const float rr = sigm(ar[i]);
            const float nn = tanh_(gn4[i] + rr * an[i]);
            const float hn = nn + zz * (*hold[i] - nn);
            *hold[i] = hn;
            ob[(size_t)i * (DDIM * TT) + t] = hn;
            hw[i * 8] = (unsigned short)f2bf_u(hn);   // i*16 bytes
        }
        // LDS-only barrier: do NOT drain vmcnt (keeps prefetch + out stores in flight)
        asm volatile("s_waitcnt lgkmcnt(0)" ::: "memory");
        __builtin_amdgcn_s_barrier();
        __builtin_amdgcn_sched_barrier(0);
    };

    for (int t = 0; t < TT - 4; t += 4) {
        substep(t + 0, 0, PZ0, PR0, PN0, true, 0 * GXSTEP);
        substep(t + 1, 1, PZ1, PR1, PN1, true, 1 * GXSTEP);
        substep(t + 2, 0, PZ2, PR2, PN2, true, 2 * GXSTEP);
        substep(t + 3, 1, PZ3, PR3, PN3, true, 3 * GXSTEP);
        gz += 4 * GXSTEP; gr += 4 * GXSTEP; gn += 4 * GXSTEP;
    }
    substep(TT - 4, 0, PZ0, PR0, PN0, false, 0);
    substep(TT - 3, 1, PZ1, PR1, PN1, false, 0);
    substep(TT - 2, 0, PZ2, PR2, PN2, false, 0);
    substep(TT - 1, 1, PZ3, PR3, PN3, false, 0);
}

// ---------------------------------------------------------------------------
// Fallback (round-1 kernel) if ws_size can't hold gx
// ---------------------------------------------------------------------------
typedef float f32x2 __attribute__((ext_vector_type(2)));

__global__ __launch_bounds__(768) void gru_fused(
    const float* __restrict__ x, const float* __restrict__ W,
    const float* __restrict__ U, const float* __restrict__ b,
    float* __restrict__ out)
{
    const int bb  = blockIdx.x;
    const int tid = threadIdx.x;
    const int kh  = (tid >= G3) ? 1 : 0;
    const int c   = tid - kh * G3;
    const int kbase = kh * 64;

    f32x2 wcol[32], ucol[32];
    #pragma unroll
    for (int k2 = 0; k2 < 32; ++k2) {
        wcol[k2][0] = W[(size_t)(kbase + 2*k2 + 0) * G3 + c];
        wcol[k2][1] = W[(size_t)(kbase + 2*k2 + 1) * G3 + c];
        ucol[k2][0] = U[(size_t)(kbase + 2*k2 + 0) * G3 + c];
        ucol[k2][1] = U[(size_t)(kbase + 2*k2 + 1) * G3 + c];
    }
    const float bias = b[c];

    __shared__ float xs[2][DDIM];
    __shared__ float hs[DDIM];
    __shared__ float px[G3], ph[G3];
    __shared__ float rs[DDIM], ns[DDIM];

    if (tid < DDIM) { hs[tid] = 0.0f; xs[0][tid] = x[((size_t)bb * DDIM + tid) * TT]; }
    __syncthreads();

    const float* __restrict__ xrow = x   + (size_t)bb * DDIM * TT;
    float* __restrict__       orow = out + (size_t)bb * DDIM * TT;
    float zv = 0.0f;

    for (int t = 0; t < TT; ++t) {
        const float* xcur = xs[t & 1] + kbase;
        const float* hcur = hs + kbase;
        f32x2 axv = {0.f, 0.f}, ahv = {0.f, 0.f};
        #pragma unroll
        for (int k2 = 0; k2 < 32; ++k2) {
            f32x2 xv = *(const f32x2*)(xcur + 2*k2);
            f32x2 hv = *(const f32x2*)(hcur + 2*k2);
            axv += xv * wcol[k2];
            ahv += hv * ucol[k2];
        }
        float ax = axv[0] + axv[1];
        float ah = ahv[0] + ahv[1];
        if (kh) { px[c] = ax; ph[c] = ah; }
        if (t + 1 < TT && tid >= 128 && tid < 256) {
            const int k = tid - 128;
            xs[(t + 1) & 1][k] = xrow[(size_t)k * TT + (t + 1)];
        }
        __syncthreads();
        if (!kh) {
            ax += px[c]; ah += ph[c];
            if (c < DDIM)            zv = sigm(ax + ah + bias);
            else if (c < 2*DDIM)     rs[c - DDIM] = sigm(ax + ah + bias);
            else { px[c] = ax + bias; ph[c] = ah; }
        }
        __syncthreads();
        if (!kh && c >= 2*DDIM) {
            float r = rs[c - 2*DDIM];
            ns[c - 2*DDIM] = tanh_(px[c] + r * ph[c]);
        }
        __syncthreads();
        if (tid < DDIM) {
            float n = ns[tid];
            float hnew = zv * hs[tid] + (1.0f - zv) * n;
            hs[tid] = hnew;
            orow[(size_t)tid * TT + t] = hnew;
        }
        __syncthreads();
    }
}

extern "C" void kernel_launch(void* const* d_in, const int* in_sizes, int n_in,
                              void* d_out, int out_size, void* d_ws, size_t ws_size,
                              hipStream_t stream) {
    const float* x = (const float*)d_in[0];
    const float* W = (const float*)d_in[1];
    const float* U = (const float*)d_in[2];
    const float* b = (const float*)d_in[3];
    float* out     = (float*)d_out;

    if (ws_size >= GX_BYTES) {
        unsigned short* gx = (unsigned short*)d_ws;
        hipLaunchKernelGGL(gx_gemm, dim3(16, 16), dim3(256), 0, stream, x, W, b, gx);
        hipLaunchKernelGGL(gru_rec, dim3(16), dim3(512), 0, stream, gx, U, out);
    } else {
        hipLaunchKernelGGL(gru_fused, dim3(256), dim3(768), 0, stream, x, W, U, b, out);
    }
}

// Round 3
// 2193.456 us; speedup vs baseline: 2.1306x; 2.1306x over previous
//
#include <hip/hip_runtime.h>

typedef float f32x4 __attribute__((ext_vector_type(4)));
typedef short bf16x8 __attribute__((ext_vector_type(8)));

#define TT    2048
#define DDIM  128
#define G3    384
#define NBBLK 16
#define GXROW 6144   /* ushorts per t per batch-block: 512 lanes * 12 */
#define GX_BYTES ((size_t)NBBLK * TT * GXROW * 2)  /* 402,653,184 B */

__device__ __forceinline__ unsigned f2bf_u(float f) {
    unsigned u = __float_as_uint(f);
    return (u + 0x7FFFu + ((u >> 16) & 1u)) >> 16;   // RNE f32->bf16
}
__device__ __forceinline__ float bf_lo(unsigned u) { return __uint_as_float(u << 16); }
__device__ __forceinline__ float bf_hi(unsigned u) { return __uint_as_float(u & 0xffff0000u); }
__device__ __forceinline__ float rcp_(float x) { return __builtin_amdgcn_rcpf(x); }
__device__ __forceinline__ float sigm_(float v) { return rcp_(1.0f + __expf(-v)); }
// tanh(u) = 2*sigmoid(2u) - 1 : saturates safely to +/-1 at both infinities
__device__ __forceinline__ float tanhf_(float v) { return 2.0f * rcp_(1.0f + __expf(-2.0f * v)) - 1.0f; }

// ---------------------------------------------------------------------------
// Kernel 1: gx[b,t,:] = x[b,:,t] @ W + b   (bf16 MFMA, full chip)
// gx layout (ushort): [bblk][t][w(8)][lane(64)][gate(3)][val(4)]
//   -> the recurrent lane reads its z/r/n uint2s from ONE 24B-aligned base.
// ---------------------------------------------------------------------------
__global__ __launch_bounds__(256) void gx_gemm(
    const float* __restrict__ x, const float* __restrict__ W,
    const float* __restrict__ bias, unsigned short* __restrict__ gx)
{
    const int bblk  = blockIdx.x;
    const int ttile = blockIdx.y;
    const int tid = threadIdx.x;
    const int w  = tid >> 6;
    const int l  = tid & 63;
    const int lc = l & 15;
    const int lk = l >> 4;

    __shared__ unsigned short xs[16 * 16 * DDIM];   // [t16][r16][d128] bf16, swizzled

    const int tiles[6] = {2*w, 2*w+1, 2*w+8, 2*w+9, 2*w+16, 2*w+17};

    bf16x8 wfrag[6][4];
    f32x4  binit[6];
    #pragma unroll
    for (int i6 = 0; i6 < 6; ++i6) {
        const int c = tiles[i6] * 16 + lc;
        const float bv = bias[c];
        binit[i6] = (f32x4){bv, bv, bv, bv};
        #pragma unroll
        for (int kt = 0; kt < 4; ++kt) {
            bf16x8 f;
            #pragma unroll
            for (int jj = 0; jj < 8; ++jj) {
                const int k = kt * 32 + lk * 8 + jj;
                f[jj] = (short)f2bf_u(W[k * G3 + c]);
            }
            wfrag[i6][kt] = f;
        }
    }

    int inoff[4];
    #pragma unroll
    for (int kt = 0; kt < 4; ++kt)
        inoff[kt] = (lc * 256 + kt * 64 + lk * 16) ^ ((lc & 7) << 4);

    const float* xb = x + (size_t)bblk * 16 * DDIM * TT;
    const int t0blk = ttile * 128;
    const int tq = tid & 3;
    const int pbase = tid >> 2;

    for (int chunk = 0; chunk < 8; ++chunk) {
        __syncthreads();
        const int t0 = t0blk + chunk * 16 + tq * 4;
        #pragma unroll 4
        for (int pp = 0; pp < 32; ++pp) {
            const int p = pbase + pp * 64;
            const int r = p >> 7, d = p & 127;
            f32x4 v = *(const f32x4*)(xb + (size_t)p * TT + t0);
            const int base = ((r * 128 + d) * 2) ^ ((r & 7) << 4);
            #pragma unroll
            for (int j = 0; j < 4; ++j) {
                const int tloc = tq * 4 + j;
                xs[(tloc * 4096 + base) >> 1] = (unsigned short)f2bf_u(v[j]);
            }
        }
        __syncthreads();

        for (int t = 0; t < 16; ++t) {
            bf16x8 a[4];
            #pragma unroll
            for (int kt = 0; kt < 4; ++kt)
                a[kt] = *(const bf16x8*)((const char*)xs + t * 4096 + inoff[kt]);

            const int tglob = t0blk + chunk * 16 + t;
            #pragma unroll
            for (int i6 = 0; i6 < 6; ++i6) {
                f32x4 acc = binit[i6];
                #pragma unroll
                for (int kt = 0; kt < 4; ++kt)
                    acc = __builtin_amdgcn_mfma_f32_16x16x32_bf16(a[kt], wfrag[i6][kt], acc, 0, 0, 0);
                unsigned p0 = f2bf_u(acc[0]) | (f2bf_u(acc[1]) << 16);
                unsigned p1 = f2bf_u(acc[2]) | (f2bf_u(acc[3]) << 16);
                const int tt6 = tiles[i6];
                const size_t off = (((size_t)bblk * TT + tglob) * 512
                                    + (size_t)((tt6 & 7) * 64 + l)) * 12 + (tt6 >> 3) * 4;
                *(uint2*)(gx + off) = make_uint2(p0, p1);
            }
        }
    }
}

// ---------------------------------------------------------------------------
// Kernel 2: sequential GRU recurrence. 16 blocks x 512 threads (8 waves).
// h in XOR-swizzled [16][128] bf16 LDS (double-buffered); out buffered in
// registers 8 steps then stored as coalesced dwordx4 (keeps vmcnt FIFO clean).
// ---------------------------------------------------------------------------
__global__ __launch_bounds__(512) void gru_rec(
    const unsigned short* __restrict__ gx, const float* __restrict__ U,
    float* __restrict__ out)
{
    const int bblk = blockIdx.x;
    const int tid  = threadIdx.x;
    const int w  = tid >> 6;
    const int l  = tid & 63;
    const int lc = l & 15, lk = l >> 4;
    const int c  = w * 16 + lc;

    // U fragments (B operand): z, r, n
    bf16x8 uz[4], ur[4], un[4];
    #pragma unroll
    for (int kt = 0; kt < 4; ++kt) {
        bf16x8 fz, fr, fn;
        #pragma unroll
        for (int jj = 0; jj < 8; ++jj) {
            const int k = kt * 32 + lk * 8 + jj;
            fz[jj] = (short)f2bf_u(U[k * G3 + c]);
            fr[jj] = (short)f2bf_u(U[k * G3 + 128 + c]);
            fn[jj] = (short)f2bf_u(U[k * G3 + 256 + c]);
        }
        uz[kt] = fz; ur[kt] = fr; un[kt] = fn;
    }

    __shared__ unsigned short hsA[2 * 2048];   // 2 bufs x [16][128] bf16, swizzled
    #pragma unroll
    for (int i = tid; i < 4096; i += 512) hsA[i] = 0;

    // A-fragment read byte-offsets (row=lc, k=kt*32+lk*8..+7), XOR-swizzled
    int roff[4];
    #pragma unroll
    for (int kt = 0; kt < 4; ++kt)
        roff[kt] = (lc * 256 + kt * 64 + lk * 16) ^ ((lc & 7) << 4);

    // h-write ushort-indices for this lane's 4 rows
    int widx[4];
    #pragma unroll
    for (int i = 0; i < 4; ++i) {
        const int r = lk * 4 + i;
        widx[i] = (r * 128 + c) ^ ((r & 7) << 3);
    }

    float hold[4] = {0.f, 0.f, 0.f, 0.f};
    float hist[4][8];

    float* obase[4];
    #pragma unroll
    for (int i = 0; i < 4; ++i)
        obase[i] = out + ((size_t)(bblk * 16 + lk * 4 + i) * DDIM + c) * TT;

    const unsigned short* g0 = gx + ((size_t)bblk * TT * 512 + (size_t)(w * 64 + l)) * 12;

    // depth-4 gx prefetch ring
    uint2 rgz[4], rgr[4], rgn[4];
    #pragma unroll
    for (int d = 0; d < 4; ++d) {
        const unsigned short* gq = g0 + (size_t)d * GXROW;
        rgz[d] = *(const uint2*)(gq);
        rgr[d] = *(const uint2*)(gq + 4);
        rgn[d] = *(const uint2*)(gq + 8);
    }

    __syncthreads();

#define GATE(I, J)                                                            \
    {                                                                         \
        const float zz = sigm_(az[I]);                                        \
        const float rr = sigm_(ar[I]);                                        \
        const float uu = gn##I + rr * an[I];                                  \
        const float nn = tanhf_(uu);                                          \
        const float hn = nn + zz * (hold[I] - nn);                            \
        hold[I] = hn;                                                         \
        hist[I][J] = hn;                                                      \
        hsA[(((J) & 1) ^ 1) * 2048 + widx[I]] = (unsigned short)f2bf_u(hn);   \
    }

#define SUBSTEP(J, DOPF)                                                      \
    {                                                                         \
        uint2 pz = rgz[(J) & 3], pr = rgr[(J) & 3], pn = rgn[(J) & 3];        \
        f32x4 az, ar;                                                         \
        az[0] = bf_lo(pz.x); az[1] = bf_hi(pz.x);                             \
        az[2] = bf_lo(pz.y); az[3] = bf_hi(pz.y);                             \
        ar[0] = bf_lo(pr.x); ar[1] = bf_hi(pr.x);                             \
        ar[2] = bf_lo(pr.y); ar[3] = bf_hi(pr.y);                             \
        const float gn0 = bf_lo(pn.x), gn1 = bf_hi(pn.x);                     \
        const float gn2 = bf_lo(pn.y), gn3 = bf_hi(pn.y);                     \
        if (DOPF) {                                                           \
            const unsigned short* gq = gpt + (size_t)((J) + 4) * GXROW;       \
            rgz[(J) & 3] = *(const uint2*)(gq);                               \
            rgr[(J) & 3] = *(const uint2*)(gq + 4);                           \
            rgn[(J) & 3] = *(const uint2*)(gq + 8);                           \
        }                                                                     \
        const char* hb = (const char*)hsA + ((J) & 1) * 4096;                 \
        bf16x8 a0 = *(const bf16x8*)(hb + roff[0]);                           \
        bf16x8 a1 = *(const bf16x8*)(hb + roff[1]);                           \
        bf16x8 a2 = *(const bf16x8*)(hb + roff[2]);                           \
        bf16x8 a3 = *(const bf16x8*)(hb + roff[3]);                           \
        f32x4 an = (f32x4){0.f, 0.f, 0.f, 0.f};                               \
        az = __builtin_amdgcn_mfma_f32_16x16x32_bf16(a0, uz[0], az, 0, 0, 0); \
        ar = __builtin_amdgcn_mfma_f32_16x16x32_bf16(a0, ur[0], ar, 0, 0, 0); \
        an = __builtin_amdgcn_mfma_f32_16x16x32_bf16(a0, un[0], an, 0, 0, 0); \
        az = __builtin_amdgcn_mfma_f32_16x16x32_bf16(a1, uz[1], az, 0, 0, 0); \
        ar = __builtin_amdgcn_mfma_f32_16x16x32_bf16(a1, ur[1], ar, 0, 0, 0); \
        an = __builtin_amdgcn_mfma_f32_16x16x32_bf16(a1, un[1], an, 0, 0, 0); \
        az = __builtin_amdgcn_mfma_f32_16x16x32_bf16(a2, uz[2], az, 0, 0, 0); \
        ar = __builtin_amdgcn_mfma_f32_16x16x32_bf16(a2, ur[2], ar, 0, 0, 0); \
        an = __builtin_amdgcn_mfma_f32_16x16x32_bf16(a2, un[2], an, 0, 0, 0); \
        az = __builtin_amdgcn_mfma_f32_16x16x32_bf16(a3, uz[3], az, 0, 0, 0); \
        ar = __builtin_amdgcn_mfma_f32_16x16x32_bf16(a3, ur[3], ar, 0, 0, 0); \
        an = __builtin_amdgcn_mfma_f32_16x16x32_bf16(a3, un[3], an, 0, 0, 0); \
        GATE(0, J) GATE(1, J) GATE(2, J) GATE(3, J)                           \
        asm volatile("s_waitcnt lgkmcnt(0)" ::: "memory");                    \
        __builtin_amdgcn_s_barrier();                                         \
        asm volatile("" ::: "memory");                                       \
    }

#define STOREHIST(T0)                                                         \
    _Pragma("unroll")                                                         \
    for (int i = 0; i < 4; ++i) {                                             \
        *(f32x4*)(obase[i] + (T0))     = (f32x4){hist[i][0], hist[i][1], hist[i][2], hist[i][3]}; \
        *(f32x4*)(obase[i] + (T0) + 4) = (f32x4){hist[i][4], hist[i][5], hist[i][6], hist[i][7]}; \
    }

    for (int t = 0; t < TT - 8; t += 8) {
        const unsigned short* gpt = g0 + (size_t)t * GXROW;
        SUBSTEP(0, true) SUBSTEP(1, true) SUBSTEP(2, true) SUBSTEP(3, true)
        SUBSTEP(4, true) SUBSTEP(5, true) SUBSTEP(6, true) SUBSTEP(7, true)
        STOREHIST(t)
    }
    {
        const int t = TT - 8;
        const unsigned short* gpt = g0 + (size_t)t * GXROW;
        SUBSTEP(0, true)  SUBSTEP(1, true)  SUBSTEP(2, true)  SUBSTEP(3, true)
        SUBSTEP(4, false) SUBSTEP(5, false) SUBSTEP(6, false) SUBSTEP(7, false)
        STOREHIST(t)
    }
#undef GATE
#undef SUBSTEP
#undef STOREHIST
}

// ---------------------------------------------------------------------------
// Fallback (round-1 kernel) if ws_size can't hold gx
// ---------------------------------------------------------------------------
typedef float f32x2 __attribute__((ext_vector_type(2)));

__global__ __launch_bounds__(768) void gru_fused(
    const float* __restrict__ x, const float* __restrict__ W,
    const float* __restrict__ U, const float* __restrict__ b,
    float* __restrict__ out)
{
    const int bb  = blockIdx.x;
    const int tid = threadIdx.x;
    const int kh  = (tid >= G3) ? 1 : 0;
    const int c   = tid - kh * G3;
    const int kbase = kh * 64;

    f32x2 wcol[32], ucol[32];
    #pragma unroll
    for (int k2 = 0; k2 < 32; ++k2) {
        wcol[k2][0] = W[(size_t)(kbase + 2*k2 + 0) * G3 + c];
        wcol[k2][1] = W[(size_t)(kbase + 2*k2 + 1) * G3 + c];
        ucol[k2][0] = U[(size_t)(kbase + 2*k2 + 0) * G3 + c];
        ucol[k2][1] = U[(size_t)(kbase + 2*k2 + 1) * G3 + c];
    }
    const float bias = b[c];

    __shared__ float xs[2][DDIM];
    __shared__ float hs[DDIM];
    __shared__ float px[G3], ph[G3];
    __shared__ float rs[DDIM], ns[DDIM];

    if (tid < DDIM) { hs[tid] = 0.0f; xs[0][tid] = x[((size_t)bb * DDIM + tid) * TT]; }
    __syncthreads();

    const float* __restrict__ xrow = x   + (size_t)bb * DDIM * TT;
    float* __restrict__       orow = out + (size_t)bb * DDIM * TT;
    float zv = 0.0f;

    for (int t = 0; t < TT; ++t) {
        const float* xcur = xs[t & 1] + kbase;
        const float* hcur = hs + kbase;
        f32x2 axv = {0.f, 0.f}, ahv = {0.f, 0.f};
        #pragma unroll
        for (int k2 = 0; k2 < 32; ++k2) {
            f32x2 xv = *(const f32x2*)(xcur + 2*k2);
            f32x2 hv = *(const f32x2*)(hcur + 2*k2);
            axv += xv * wcol[k2];
            ahv += hv * ucol[k2];
        }
        float ax = axv[0] + axv[1];
        float ah = ahv[0] + ahv[1];
        if (kh) { px[c] = ax; ph[c] = ah; }
        if (t + 1 < TT && tid >= 128 && tid < 256) {
            const int k = tid - 128;
            xs[(t + 1) & 1][k] = xrow[(size_t)k * TT + (t + 1)];
        }
        __syncthreads();
        if (!kh) {
            ax += px[c]; ah += ph[c];
            if (c < DDIM)            zv = sigm_(ax + ah + bias);
            else if (c < 2*DDIM)     rs[c - DDIM] = sigm_(ax + ah + bias);
            else { px[c] = ax + bias; ph[c] = ah; }
        }
        __syncthreads();
        if (!kh && c >= 2*DDIM) {
            float r = rs[c - 2*DDIM];
            ns[c - 2*DDIM] = tanhf_(px[c] + r * ph[c]);
        }
        __syncthreads();
        if (tid < DDIM) {
            float n = ns[tid];
            float hnew = zv * hs[tid] + (1.0f - zv) * n;
            hs[tid] = hnew;
            orow[(size_t)tid * TT + t] = hnew;
        }
        __syncthreads();
    }
}

extern "C" void kernel_launch(void* const* d_in, const int* in_sizes, int n_in,
                              void* d_out, int out_size, void* d_ws, size_t ws_size,
                              hipStream_t stream) {
    const float* x = (const float*)d_in[0];
    const float* W = (const float*)d_in[1];
    const float* U = (const float*)d_in[2];
    const float* b = (const float*)d_in[3];
    float* out     = (float*)d_out;

    if (ws_size >= GX_BYTES) {
        unsigned short* gx = (unsigned short*)d_ws;
        hipLaunchKernelGGL(gx_gemm, dim3(16, 16), dim3(256), 0, stream, x, W, b, gx);
        hipLaunchKernelGGL(gru_rec, dim3(16), dim3(512), 0, stream, gx, U, out);
    } else {
        hipLaunchKernelGGL(gru_fused, dim3(256), dim3(768), 0, stream, x, W, U, b, out);
    }
}

// Round 4
// 1811.922 us; speedup vs baseline: 2.5793x; 1.2106x over previous
//
#include <hip/hip_runtime.h>

typedef float f32x4 __attribute__((ext_vector_type(4)));
typedef short bf16x8 __attribute__((ext_vector_type(8)));

#define TT    2048
#define DDIM  128
#define G3    384
#define NBBLK 16
#define GXROW 6144   /* ushorts per t per batch-block: 8 cb * 768 */
#define GX_BYTES ((size_t)NBBLK * TT * GXROW * 2)  /* 402,653,184 B */

__device__ __forceinline__ unsigned f2bf_u(float f) {
    unsigned u = __float_as_uint(f);
    return (u + 0x7FFFu + ((u >> 16) & 1u)) >> 16;   // RNE f32->bf16
}
__device__ __forceinline__ float bf_lo(unsigned u) { return __uint_as_float(u << 16); }
__device__ __forceinline__ float bf_hi(unsigned u) { return __uint_as_float(u & 0xffff0000u); }
__device__ __forceinline__ float rcp_(float x) { return __builtin_amdgcn_rcpf(x); }
__device__ __forceinline__ float sigm_(float v) { return rcp_(1.0f + __expf(-v)); }
__device__ __forceinline__ float tanhf_(float v) { return 2.0f * rcp_(1.0f + __expf(-2.0f * v)) - 1.0f; }

// ---------------------------------------------------------------------------
// Kernel 1: gx[b,t,:] = x[b,:,t] @ W + b   (bf16 MFMA, full chip)
// gx layout (ushort), SoA-by-gate for coalesced 8B-stride consumer loads:
//   [bblk][t][cb(8)][gate(3)][lane(64)][val(4)]   (768 ushorts per (t,cb))
// ---------------------------------------------------------------------------
__global__ __launch_bounds__(256) void gx_gemm(
    const float* __restrict__ x, const float* __restrict__ W,
    const float* __restrict__ bias, unsigned short* __restrict__ gx)
{
    const int bblk  = blockIdx.x;
    const int ttile = blockIdx.y;
    const int tid = threadIdx.x;
    const int w  = tid >> 6;
    const int l  = tid & 63;
    const int lc = l & 15;
    const int lk = l >> 4;

    __shared__ unsigned short xs[16 * 16 * DDIM];   // [t16][r16][d128] bf16, swizzled

    const int tiles[6] = {2*w, 2*w+1, 2*w+8, 2*w+9, 2*w+16, 2*w+17};

    bf16x8 wfrag[6][4];
    f32x4  binit[6];
    #pragma unroll
    for (int i6 = 0; i6 < 6; ++i6) {
        const int c = tiles[i6] * 16 + lc;
        const float bv = bias[c];
        binit[i6] = (f32x4){bv, bv, bv, bv};
        #pragma unroll
        for (int kt = 0; kt < 4; ++kt) {
            bf16x8 f;
            #pragma unroll
            for (int jj = 0; jj < 8; ++jj) {
                const int k = kt * 32 + lk * 8 + jj;
                f[jj] = (short)f2bf_u(W[k * G3 + c]);
            }
            wfrag[i6][kt] = f;
        }
    }

    int inoff[4];
    #pragma unroll
    for (int kt = 0; kt < 4; ++kt)
        inoff[kt] = (lc * 256 + kt * 64 + lk * 16) ^ ((lc & 7) << 4);

    const float* xb = x + (size_t)bblk * 16 * DDIM * TT;
    const int t0blk = ttile * 128;
    const int tq = tid & 3;
    const int pbase = tid >> 2;

    for (int chunk = 0; chunk < 8; ++chunk) {
        __syncthreads();
        const int t0 = t0blk + chunk * 16 + tq * 4;
        #pragma unroll 4
        for (int pp = 0; pp < 32; ++pp) {
            const int p = pbase + pp * 64;
            const int r = p >> 7, d = p & 127;
            f32x4 v = *(const f32x4*)(xb + (size_t)p * TT + t0);
            const int base = ((r * 128 + d) * 2) ^ ((r & 7) << 4);
            #pragma unroll
            for (int j = 0; j < 4; ++j) {
                const int tloc = tq * 4 + j;
                xs[(tloc * 4096 + base) >> 1] = (unsigned short)f2bf_u(v[j]);
            }
        }
        __syncthreads();

        for (int t = 0; t < 16; ++t) {
            bf16x8 a[4];
            #pragma unroll
            for (int kt = 0; kt < 4; ++kt)
                a[kt] = *(const bf16x8*)((const char*)xs + t * 4096 + inoff[kt]);

            const int tglob = t0blk + chunk * 16 + t;
            #pragma unroll
            for (int i6 = 0; i6 < 6; ++i6) {
                f32x4 acc = binit[i6];
                #pragma unroll
                for (int kt = 0; kt < 4; ++kt)
                    acc = __builtin_amdgcn_mfma_f32_16x16x32_bf16(a[kt], wfrag[i6][kt], acc, 0, 0, 0);
                unsigned p0 = f2bf_u(acc[0]) | (f2bf_u(acc[1]) << 16);
                unsigned p1 = f2bf_u(acc[2]) | (f2bf_u(acc[3]) << 16);
                const int tt6 = tiles[i6];
                const int cb = tt6 & 7, g = tt6 >> 3;
                const size_t off = ((size_t)(bblk * TT + tglob) * 8 + cb) * 768
                                   + g * 256 + l * 4;
                *(uint2*)(gx + off) = make_uint2(p0, p1);   // 8B lane-stride, coalesced
            }
        }
    }
}

// ---------------------------------------------------------------------------
// Kernel 2: sequential GRU recurrence. 16 blocks x 512 threads (8 waves).
// h: XOR-swizzled [16][128] bf16 LDS double-buffer. out: staged 16 steps in a
// 128KB LDS tile [t16][row16][c128], flushed as coalesced 64B-run dwordx4
// stores (4 lanes per (row,c)) -> ~4x fewer scattered-line touches.
// gx: SoA-by-gate, 3 coalesced uint2 loads/lane/step, depth-4 prefetch ring.
// ---------------------------------------------------------------------------
__global__ __launch_bounds__(512, 2) void gru_rec(
    const unsigned short* __restrict__ gx, const float* __restrict__ U,
    float* __restrict__ out)
{
    const int bblk = blockIdx.x;
    const int tid  = threadIdx.x;
    const int w  = tid >> 6;
    const int l  = tid & 63;
    const int lc = l & 15, lk = l >> 4;
    const int c  = w * 16 + lc;

    // U fragments (B operand): z, r, n
    bf16x8 uz[4], ur[4], un[4];
    #pragma unroll
    for (int kt = 0; kt < 4; ++kt) {
        bf16x8 fz, fr, fn;
        #pragma unroll
        for (int jj = 0; jj < 8; ++jj) {
            const int k = kt * 32 + lk * 8 + jj;
            fz[jj] = (short)f2bf_u(U[k * G3 + c]);
            fr[jj] = (short)f2bf_u(U[k * G3 + 128 + c]);
            fn[jj] = (short)f2bf_u(U[k * G3 + 256 + c]);
        }
        uz[kt] = fz; ur[kt] = fr; un[kt] = fn;
    }

    __shared__ unsigned short hsA[2 * 2048];   // 8KB: 2 bufs x [16][128] bf16, swizzled
    __shared__ float hlds[16 * 16 * 128];      // 128KB: [t16][row16][c128], swizzled
    #pragma unroll
    for (int i = tid; i < 4096; i += 512) hsA[i] = 0;

    int roff[4];
    #pragma unroll
    for (int kt = 0; kt < 4; ++kt)
        roff[kt] = (lc * 256 + kt * 64 + lk * 16) ^ ((lc & 7) << 4);

    int widx[4];   // h-write ushort-indices (swizzled [16][128])
    int hwi[4];    // hlds write float-indices (row*128 + swizzled c)
    #pragma unroll
    for (int i = 0; i < 4; ++i) {
        const int r = lk * 4 + i;
        widx[i] = (r * 128 + c) ^ ((r & 7) << 3);
        hwi[i]  = r * 128 + (c ^ ((r & 7) << 2));
    }

    float hold[4] = {0.f, 0.f, 0.f, 0.f};

    // gx lane base: [bblk][t][cb=w][gate][lane][4]
    const unsigned short* g0 = gx + ((size_t)bblk * TT * 8 + w) * 768 + l * 4;

    // flush mapping: 4 lanes per (row,c): lane -> c = w*16 + (l>>2), t-chunk q = l&3
    const int cfl = w * 16 + (l >> 2);
    const int qfl = l & 3;
    float* outfl = out + ((size_t)(bblk * 16) * DDIM + cfl) * TT + qfl * 4;

    // depth-4 gx prefetch ring
    uint2 rgz[4], rgr[4], rgn[4];
    #pragma unroll
    for (int d = 0; d < 4; ++d) {
        const unsigned short* gq = g0 + (size_t)d * GXROW;
        rgz[d] = *(const uint2*)(gq);
        rgr[d] = *(const uint2*)(gq + 256);
        rgn[d] = *(const uint2*)(gq + 512);
    }

    __syncthreads();

#define GATE(I, J)                                                            \
    {                                                                         \
        const float zz = sigm_(az[I]);                                        \
        const float rr = sigm_(ar[I]);                                        \
        const float uu = gn##I + rr * an[I];                                  \
        const float nn = tanhf_(uu);                                          \
        const float hn = nn + zz * (hold[I] - nn);                            \
        hold[I] = hn;                                                         \
        hlds[(J) * 2048 + hwi[I]] = hn;                                       \
        hsA[(((J) & 1) ^ 1) * 2048 + widx[I]] = (unsigned short)f2bf_u(hn);   \
    }

#define SUBSTEP(J, DOPF)                                                      \
    {                                                                         \
        uint2 pz = rgz[(J) & 3], pr = rgr[(J) & 3], pn = rgn[(J) & 3];        \
        f32x4 az, ar;                                                         \
        az[0] = bf_lo(pz.x); az[1] = bf_hi(pz.x);                             \
        az[2] = bf_lo(pz.y); az[3] = bf_hi(pz.y);                             \
        ar[0] = bf_lo(pr.x); ar[1] = bf_hi(pr.x);                             \
        ar[2] = bf_lo(pr.y); ar[3] = bf_hi(pr.y);                             \
        const float gn0 = bf_lo(pn.x), gn1 = bf_hi(pn.x);                     \
        const float gn2 = bf_lo(pn.y), gn3 = bf_hi(pn.y);                     \
        if (DOPF) {                                                           \
            const unsigned short* gq = gpt + (size_t)((J) + 4) * GXROW;       \
            rgz[(J) & 3] = *(const uint2*)(gq);                               \
            rgr[(J) & 3] = *(const uint2*)(gq + 256);                         \
            rgn[(J) & 3] = *(const uint2*)(gq + 512);                         \
        }                                                                     \
        const char* hb = (const char*)hsA + ((J) & 1) * 4096;                 \
        bf16x8 a0 = *(const bf16x8*)(hb + roff[0]);                           \
        bf16x8 a1 = *(const bf16x8*)(hb + roff[1]);                           \
        bf16x8 a2 = *(const bf16x8*)(hb + roff[2]);                           \
        bf16x8 a3 = *(const bf16x8*)(hb + roff[3]);                           \
        f32x4 an = (f32x4){0.f, 0.f, 0.f, 0.f};                               \
        az = __builtin_amdgcn_mfma_f32_16x16x32_bf16(a0, uz[0], az, 0, 0, 0); \
        ar = __builtin_amdgcn_mfma_f32_16x16x32_bf16(a0, ur[0], ar, 0, 0, 0); \
        an = __builtin_amdgcn_mfma_f32_16x16x32_bf16(a0, un[0], an, 0, 0, 0); \
        az = __builtin_amdgcn_mfma_f32_16x16x32_bf16(a1, uz[1], az, 0, 0, 0); \
        ar = __builtin_amdgcn_mfma_f32_16x16x32_bf16(a1, ur[1], ar, 0, 0, 0); \
        an = __builtin_amdgcn_mfma_f32_16x16x32_bf16(a1, un[1], an, 0, 0, 0); \
        az = __builtin_amdgcn_mfma_f32_16x16x32_bf16(a2, uz[2], az, 0, 0, 0); \
        ar = __builtin_amdgcn_mfma_f32_16x16x32_bf16(a2, ur[2], ar, 0, 0, 0); \
        an = __builtin_amdgcn_mfma_f32_16x16x32_bf16(a2, un[2], an, 0, 0, 0); \
        az = __builtin_amdgcn_mfma_f32_16x16x32_bf16(a3, uz[3], az, 0, 0, 0); \
        ar = __builtin_amdgcn_mfma_f32_16x16x32_bf16(a3, ur[3], ar, 0, 0, 0); \
        an = __builtin_amdgcn_mfma_f32_16x16x32_bf16(a3, un[3], an, 0, 0, 0); \
        GATE(0, J) GATE(1, J) GATE(2, J) GATE(3, J)                           \
        asm volatile("s_waitcnt lgkmcnt(0)" ::: "memory");                    \
        __builtin_amdgcn_s_barrier();                                         \
    }

    // flush: own-wave data only -> no barrier needed.  16 rounds: round r
    // stores row r, 16 c-columns, 4 lanes per c covering the 64B t-run.
#define FLUSH(T0)                                                             \
    _Pragma("unroll")                                                         \
    for (int r = 0; r < 16; ++r) {                                            \
        const int fr = r * 128 + (cfl ^ ((r & 7) << 2));                      \
        f32x4 v;                                                              \
        v[0] = hlds[(qfl * 4 + 0) * 2048 + fr];                               \
        v[1] = hlds[(qfl * 4 + 1) * 2048 + fr];                               \
        v[2] = hlds[(qfl * 4 + 2) * 2048 + fr];                               \
        v[3] = hlds[(qfl * 4 + 3) * 2048 + fr];                               \
        *(f32x4*)(outfl + (size_t)r * (DDIM * TT) + (T0)) = v;                \
    }

    for (int t = 0; t < TT - 16; t += 16) {
        const unsigned short* gpt = g0 + (size_t)t * GXROW;
        SUBSTEP(0, true)  SUBSTEP(1, true)  SUBSTEP(2, true)  SUBSTEP(3, true)
        SUBSTEP(4, true)  SUBSTEP(5, true)  SUBSTEP(6, true)  SUBSTEP(7, true)
        SUBSTEP(8, true)  SUBSTEP(9, true)  SUBSTEP(10, true) SUBSTEP(11, true)
        SUBSTEP(12, true) SUBSTEP(13, true) SUBSTEP(14, true) SUBSTEP(15, true)
        FLUSH(t)
    }
    {
        const int t = TT - 16;
        const unsigned short* gpt = g0 + (size_t)t * GXROW;
        SUBSTEP(0, true)  SUBSTEP(1, true)  SUBSTEP(2, true)  SUBSTEP(3, true)
        SUBSTEP(4, true)  SUBSTEP(5, true)  SUBSTEP(6, true)  SUBSTEP(7, true)
        SUBSTEP(8, true)  SUBSTEP(9, true)  SUBSTEP(10, true) SUBSTEP(11, true)
        SUBSTEP(12, false) SUBSTEP(13, false) SUBSTEP(14, false) SUBSTEP(15, false)
        FLUSH(t)
    }
#undef GATE
#undef SUBSTEP
#undef FLUSH
}

// ---------------------------------------------------------------------------
// Fallback (round-1 kernel) if ws_size can't hold gx
// ---------------------------------------------------------------------------
typedef float f32x2 __attribute__((ext_vector_type(2)));

__global__ __launch_bounds__(768) void gru_fused(
    const float* __restrict__ x, const float* __restrict__ W,
    const float* __restrict__ U, const float* __restrict__ b,
    float* __restrict__ out)
{
    const int bb  = blockIdx.x;
    const int tid = threadIdx.x;
    const int kh  = (tid >= G3) ? 1 : 0;
    const int c   = tid - kh * G3;
    const int kbase = kh * 64;

    f32x2 wcol[32], ucol[32];
    #pragma unroll
    for (int k2 = 0; k2 < 32; ++k2) {
        wcol[k2][0] = W[(size_t)(kbase + 2*k2 + 0) * G3 + c];
        wcol[k2][1] = W[(size_t)(kbase + 2*k2 + 1) * G3 + c];
        ucol[k2][0] = U[(size_t)(kbase + 2*k2 + 0) * G3 + c];
        ucol[k2][1] = U[(size_t)(kbase + 2*k2 + 1) * G3 + c];
    }
    const float bias = b[c];

    __shared__ float xs[2][DDIM];
    __shared__ float hs[DDIM];
    __shared__ float px[G3], ph[G3];
    __shared__ float rs[DDIM], ns[DDIM];

    if (tid < DDIM) { hs[tid] = 0.0f; xs[0][tid] = x[((size_t)bb * DDIM + tid) * TT]; }
    __syncthreads();

    const float* __restrict__ xrow = x   + (size_t)bb * DDIM * TT;
    float* __restrict__       orow = out + (size_t)bb * DDIM * TT;
    float zv = 0.0f;

    for (int t = 0; t < TT; ++t) {
        const float* xcur = xs[t & 1] + kbase;
        const float* hcur = hs + kbase;
        f32x2 axv = {0.f, 0.f}, ahv = {0.f, 0.f};
        #pragma unroll
        for (int k2 = 0; k2 < 32; ++k2) {
            f32x2 xv = *(const f32x2*)(xcur + 2*k2);
            f32x2 hv = *(const f32x2*)(hcur + 2*k2);
            axv += xv * wcol[k2];
            ahv += hv * ucol[k2];
        }
        float ax = axv[0] + axv[1];
        float ah = ahv[0] + ahv[1];
        if (kh) { px[c] = ax; ph[c] = ah; }
        if (t + 1 < TT && tid >= 128 && tid < 256) {
            const int k = tid - 128;
            xs[(t + 1) & 1][k] = xrow[(size_t)k * TT + (t + 1)];
        }
        __syncthreads();
        if (!kh) {
            ax += px[c]; ah += ph[c];
            if (c < DDIM)            zv = sigm_(ax + ah + bias);
            else if (c < 2*DDIM)     rs[c - DDIM] = sigm_(ax + ah + bias);
            else { px[c] = ax + bias; ph[c] = ah; }
        }
        __syncthreads();
        if (!kh && c >= 2*DDIM) {
            float r = rs[c - 2*DDIM];
            ns[c - 2*DDIM] = tanhf_(px[c] + r * ph[c]);
        }
        __syncthreads();
        if (tid < DDIM) {
            float n = ns[tid];
            float hnew = zv * hs[tid] + (1.0f - zv) * n;
            hs[tid] = hnew;
            orow[(size_t)tid * TT + t] = hnew;
        }
        __syncthreads();
    }
}

extern "C" void kernel_launch(void* const* d_in, const int* in_sizes, int n_in,
                              void* d_out, int out_size, void* d_ws, size_t ws_size,
                              hipStream_t stream) {
    const float* x = (const float*)d_in[0];
    const float* W = (const float*)d_in[1];
    const float* U = (const float*)d_in[2];
    const float* b = (const float*)d_in[3];
    float* out     = (float*)d_out;

    if (ws_size >= GX_BYTES) {
        unsigned short* gx = (unsigned short*)d_ws;
        hipLaunchKernelGGL(gx_gemm, dim3(16, 16), dim3(256), 0, stream, x, W, b, gx);
        hipLaunchKernelGGL(gru_rec, dim3(16), dim3(512), 0, stream, gx, U, out);
    } else {
        hipLaunchKernelGGL(gru_fused, dim3(256), dim3(768), 0, stream, x, W, U, b, out);
    }
}

// Round 6
// 1797.151 us; speedup vs baseline: 2.6005x; 1.0082x over previous
//
#include <hip/hip_runtime.h>

typedef float f32x4 __attribute__((ext_vector_type(4)));
typedef short bf16x8 __attribute__((ext_vector_type(8)));

#define TT    2048
#define DDIM  128
#define G3    384
#define NBBLK 16
#define GXROW 6144   /* ushorts per t per batch-block: 8 cb * 768 */
#define GX_BYTES ((size_t)NBBLK * TT * GXROW * 2)  /* 402,653,184 B */

__device__ __forceinline__ unsigned f2bf_u(float f) {
    unsigned u = __float_as_uint(f);
    return (u + 0x7FFFu + ((u >> 16) & 1u)) >> 16;   // RNE f32->bf16
}
__device__ __forceinline__ float bf_lo(unsigned u) { return __uint_as_float(u << 16); }
__device__ __forceinline__ float bf_hi(unsigned u) { return __uint_as_float(u & 0xffff0000u); }
__device__ __forceinline__ float rcp_(float x) { return __builtin_amdgcn_rcpf(x); }
__device__ __forceinline__ float sigm_(float v) { return rcp_(1.0f + __expf(-v)); }
__device__ __forceinline__ float tanhf_(float v) { return 2.0f * rcp_(1.0f + __expf(-2.0f * v)) - 1.0f; }
// register-only asm (no LDS addressing) -> safe
__device__ __forceinline__ unsigned cvt_pk_bf16(float lo, float hi) {
    unsigned d;
    asm("v_cvt_pk_bf16_f32 %0, %1, %2" : "=v"(d) : "v"(lo), "v"(hi));
    return d;
}

// ---------------------------------------------------------------------------
// Kernel 1: gx[b,t,:] = x[b,:,t] @ W + b   (bf16 MFMA, full chip)
// gx layout (ushort), SoA-by-gate for coalesced 8B-stride consumer loads:
//   [bblk][t][cb(8)][gate(3)][lane(64)][val(4)]   (768 ushorts per (t,cb))
// ---------------------------------------------------------------------------
__global__ __launch_bounds__(256) void gx_gemm(
    const float* __restrict__ x, const float* __restrict__ W,
    const float* __restrict__ bias, unsigned short* __restrict__ gx)
{
    const int bblk  = blockIdx.x;
    const int ttile = blockIdx.y;
    const int tid = threadIdx.x;
    const int w  = tid >> 6;
    const int l  = tid & 63;
    const int lc = l & 15;
    const int lk = l >> 4;

    __shared__ unsigned short xs[16 * 16 * DDIM];   // [t16][r16][d128] bf16, swizzled

    const int tiles[6] = {2*w, 2*w+1, 2*w+8, 2*w+9, 2*w+16, 2*w+17};

    bf16x8 wfrag[6][4];
    f32x4  binit[6];
    #pragma unroll
    for (int i6 = 0; i6 < 6; ++i6) {
        const int c = tiles[i6] * 16 + lc;
        const float bv = bias[c];
        binit[i6] = (f32x4){bv, bv, bv, bv};
        #pragma unroll
        for (int kt = 0; kt < 4; ++kt) {
            bf16x8 f;
            #pragma unroll
            for (int jj = 0; jj < 8; ++jj) {
                const int k = kt * 32 + lk * 8 + jj;
                f[jj] = (short)f2bf_u(W[k * G3 + c]);
            }
            wfrag[i6][kt] = f;
        }
    }

    int inoff[4];
    #pragma unroll
    for (int kt = 0; kt < 4; ++kt)
        inoff[kt] = (lc * 256 + kt * 64 + lk * 16) ^ ((lc & 7) << 4);

    const float* xb = x + (size_t)bblk * 16 * DDIM * TT;
    const int t0blk = ttile * 128;
    const int tq = tid & 3;
    const int pbase = tid >> 2;

    for (int chunk = 0; chunk < 8; ++chunk) {
        __syncthreads();
        const int t0 = t0blk + chunk * 16 + tq * 4;
        #pragma unroll 4
        for (int pp = 0; pp < 32; ++pp) {
            const int p = pbase + pp * 64;
            const int r = p >> 7, d = p & 127;
            f32x4 v = *(const f32x4*)(xb + (size_t)p * TT + t0);
            char* bp = (char*)xs + (tq * 4) * 4096 + (((r * 128 + d) * 2) ^ ((r & 7) << 4));
            const unsigned pkA = cvt_pk_bf16(v[0], v[1]);
            const unsigned pkB = cvt_pk_bf16(v[2], v[3]);
            *(unsigned short*)(bp)         = (unsigned short)pkA;
            *(unsigned short*)(bp + 4096)  = (unsigned short)(pkA >> 16);
            *(unsigned short*)(bp + 8192)  = (unsigned short)pkB;
            *(unsigned short*)(bp + 12288) = (unsigned short)(pkB >> 16);
        }
        __syncthreads();

        for (int t = 0; t < 16; ++t) {
            bf16x8 a[4];
            #pragma unroll
            for (int kt = 0; kt < 4; ++kt)
                a[kt] = *(const bf16x8*)((const char*)xs + t * 4096 + inoff[kt]);

            const int tglob = t0blk + chunk * 16 + t;
            #pragma unroll
            for (int i6 = 0; i6 < 6; ++i6) {
                f32x4 acc = binit[i6];
                #pragma unroll
                for (int kt = 0; kt < 4; ++kt)
                    acc = __builtin_amdgcn_mfma_f32_16x16x32_bf16(a[kt], wfrag[i6][kt], acc, 0, 0, 0);
                unsigned p0 = cvt_pk_bf16(acc[0], acc[1]);
                unsigned p1 = cvt_pk_bf16(acc[2], acc[3]);
                const int tt6 = tiles[i6];
                const int cb = tt6 & 7, g = tt6 >> 3;
                const size_t off = ((size_t)(bblk * TT + tglob) * 8 + cb) * 768
                                   + g * 256 + l * 4;
                *(uint2*)(gx + off) = make_uint2(p0, p1);   // 8B lane-stride, coalesced
            }
        }
    }
}

// ---------------------------------------------------------------------------
// Kernel 2: sequential GRU recurrence. 16 blocks x 512 threads (8 waves).
// h: XOR-swizzled [16][128] bf16 LDS double-buffer (cvt_pk + plain b16 writes).
// out: staged 16 steps in 128KB LDS [t16][r16][c128] with (8*(r>>2) + 8*(t>>2))
// column rotation -> all LDS write/read insts 2-way-or-better (free).
// gx: SoA-by-gate, depth-4 register prefetch ring.
// ---------------------------------------------------------------------------
__global__ __launch_bounds__(512, 2) void gru_rec(
    const unsigned short* __restrict__ gx, const float* __restrict__ U,
    float* __restrict__ out)
{
    const int bblk = blockIdx.x;
    const int tid  = threadIdx.x;
    const int w  = tid >> 6;
    const int l  = tid & 63;
    const int lc = l & 15, lk = l >> 4;
    const int c  = w * 16 + lc;

    // U fragments (B operand): z, r, n
    bf16x8 uz[4], ur[4], un[4];
    #pragma unroll
    for (int kt = 0; kt < 4; ++kt) {
        bf16x8 fz, fr, fn;
        #pragma unroll
        for (int jj = 0; jj < 8; ++jj) {
            const int k = kt * 32 + lk * 8 + jj;
            fz[jj] = (short)f2bf_u(U[k * G3 + c]);
            fr[jj] = (short)f2bf_u(U[k * G3 + 128 + c]);
            fn[jj] = (short)f2bf_u(U[k * G3 + 256 + c]);
        }
        uz[kt] = fz; ur[kt] = fr; un[kt] = fn;
    }

    __shared__ unsigned short hsA[2 * 2048];   // 8KB: 2 bufs x [16][128] bf16, swizzled
    __shared__ float hlds[16 * 16 * 128];      // 128KB out staging
    #pragma unroll
    for (int i = tid; i < 4096; i += 512) hsA[i] = 0;
    char* const hb_lds = (char*)hlds;

    int roff[4];   // A-frag read byte offsets
    #pragma unroll
    for (int kt = 0; kt < 4; ++kt)
        roff[kt] = (lc * 256 + kt * 64 + lk * 16) ^ ((lc & 7) << 4);

    unsigned widxB[4];   // hsA write BYTE offsets (within buf 0)
    #pragma unroll
    for (int i = 0; i < 4; ++i) {
        const int r = lk * 4 + i;
        widxB[i] = (unsigned)(((r * 128 + c) ^ ((r & 7) << 3)) * 2);
    }

    // hlds write byte addrs: [s=J>>2][i]; (J&3)*8192 added as immediate
    int hl_addr[4][4];
    #pragma unroll
    for (int s = 0; s < 4; ++s)
        #pragma unroll
        for (int i = 0; i < 4; ++i) {
            const int r = lk * 4 + i;
            hl_addr[s][i] = s * 32768 + (r * 128 + ((c + 8 * lk + 8 * s) & 127)) * 4;
        }

    // flush read bases: lane covers (cfl, qfl)
    const int cfl = w * 16 + (l >> 2);
    const int qfl = l & 3;
    int fl_base[4];
    #pragma unroll
    for (int g = 0; g < 4; ++g)
        fl_base[g] = qfl * 32768 + ((cfl + 8 * g + 8 * qfl) & 127) * 4;

    float hold[4] = {0.f, 0.f, 0.f, 0.f};

    const unsigned short* g0 = gx + ((size_t)bblk * TT * 8 + w) * 768 + l * 4;
    float* outb = out + (size_t)(bblk * 16) * DDIM * TT;

    // depth-4 gx prefetch ring
    uint2 rgz[4], rgr[4], rgn[4];
    #pragma unroll
    for (int d = 0; d < 4; ++d) {
        const unsigned short* gq = g0 + (size_t)d * GXROW;
        rgz[d] = *(const uint2*)(gq);
        rgr[d] = *(const uint2*)(gq + 256);
        rgn[d] = *(const uint2*)(gq + 512);
    }

    __syncthreads();

#define GATE(I, J)                                                            \
    {                                                                         \
        const float zz = sigm_(az_a[I] + az_b[I]);                            \
        const float rr = sigm_(ar_a[I] + ar_b[I]);                            \
        const float uu = gn##I + rr * (an_a[I] + an_b[I]);                    \
        const float nn = tanhf_(uu);                                          \
        const float hn = nn + zz * (hold[I] - nn);                            \
        hold[I] = hn;                                                         \
        *(float*)(hb_lds + hl_addr[(J) >> 2][I] + ((J) & 3) * 8192) = hn;     \
        hh[I] = hn;                                                           \
    }

#define SUBSTEP(J, DOPF)                                                      \
    {                                                                         \
        const char* hb = (const char*)hsA + ((J) & 1) * 4096;                 \
        bf16x8 a0 = *(const bf16x8*)(hb + roff[0]);                           \
        bf16x8 a1 = *(const bf16x8*)(hb + roff[1]);                           \
        bf16x8 a2 = *(const bf16x8*)(hb + roff[2]);                           \
        bf16x8 a3 = *(const bf16x8*)(hb + roff[3]);                           \
        uint2 pz = rgz[(J) & 3], pr = rgr[(J) & 3], pn = rgn[(J) & 3];        \
        if (DOPF) {                                                           \
            const unsigned short* gq = gpt + (size_t)((J) + 4) * GXROW;       \
            rgz[(J) & 3] = *(const uint2*)(gq);                               \
            rgr[(J) & 3] = *(const uint2*)(gq + 256);                         \
            rgn[(J) & 3] = *(const uint2*)(gq + 512);                         \
        }                                                                     \
        f32x4 az_a, ar_a;                                                     \
        az_a[0] = bf_lo(pz.x); az_a[1] = bf_hi(pz.x);                         \
        az_a[2] = bf_lo(pz.y); az_a[3] = bf_hi(pz.y);                         \
        ar_a[0] = bf_lo(pr.x); ar_a[1] = bf_hi(pr.x);                         \
        ar_a[2] = bf_lo(pr.y); ar_a[3] = bf_hi(pr.y);                         \
        const float gn0 = bf_lo(pn.x), gn1 = bf_hi(pn.x);                     \
        const float gn2 = bf_lo(pn.y), gn3 = bf_hi(pn.y);                     \
        f32x4 an_a = (f32x4){0.f, 0.f, 0.f, 0.f};                             \
        f32x4 an_b = an_a, az_b = an_a, ar_b = an_a;                          \
        an_a = __builtin_amdgcn_mfma_f32_16x16x32_bf16(a0, un[0], an_a, 0, 0, 0); \
        an_b = __builtin_amdgcn_mfma_f32_16x16x32_bf16(a2, un[2], an_b, 0, 0, 0); \
        az_a = __builtin_amdgcn_mfma_f32_16x16x32_bf16(a0, uz[0], az_a, 0, 0, 0); \
        az_b = __builtin_amdgcn_mfma_f32_16x16x32_bf16(a2, uz[2], az_b, 0, 0, 0); \
        ar_a = __builtin_amdgcn_mfma_f32_16x16x32_bf16(a0, ur[0], ar_a, 0, 0, 0); \
        ar_b = __builtin_amdgcn_mfma_f32_16x16x32_bf16(a2, ur[2], ar_b, 0, 0, 0); \
        an_a = __builtin_amdgcn_mfma_f32_16x16x32_bf16(a1, un[1], an_a, 0, 0, 0); \
        an_b = __builtin_amdgcn_mfma_f32_16x16x32_bf16(a3, un[3], an_b, 0, 0, 0); \
        az_a = __builtin_amdgcn_mfma_f32_16x16x32_bf16(a1, uz[1], az_a, 0, 0, 0); \
        az_b = __builtin_amdgcn_mfma_f32_16x16x32_bf16(a3, uz[3], az_b, 0, 0, 0); \
        ar_a = __builtin_amdgcn_mfma_f32_16x16x32_bf16(a1, ur[1], ar_a, 0, 0, 0); \
        ar_b = __builtin_amdgcn_mfma_f32_16x16x32_bf16(a3, ur[3], ar_b, 0, 0, 0); \
        float hh[4];                                                          \
        GATE(0, J) GATE(1, J) GATE(2, J) GATE(3, J)                           \
        {                                                                     \
            char* hwb = (char*)hsA + (((J) & 1) ^ 1) * 4096;                  \
            const unsigned pk01 = cvt_pk_bf16(hh[0], hh[1]);                  \
            const unsigned pk23 = cvt_pk_bf16(hh[2], hh[3]);                  \
            *(unsigned short*)(hwb + widxB[0]) = (unsigned short)pk01;        \
            *(unsigned short*)(hwb + widxB[1]) = (unsigned short)(pk01 >> 16);\
            *(unsigned short*)(hwb + widxB[2]) = (unsigned short)pk23;        \
            *(unsigned short*)(hwb + widxB[3]) = (unsigned short)(pk23 >> 16);\
        }                                                                     \
        asm volatile("s_waitcnt lgkmcnt(0)" ::: "memory");                    \
        __builtin_amdgcn_s_barrier();                                         \
    }

    // flush: own-wave data only -> no barrier needed
#define FLUSH(T0)                                                             \
    _Pragma("unroll")                                                         \
    for (int r = 0; r < 16; ++r) {                                            \
        f32x4 v;                                                              \
        _Pragma("unroll")                                                     \
        for (int k = 0; k < 4; ++k)                                           \
            v[k] = *(const float*)(hb_lds + fl_base[r >> 2] + r * 512 + k * 8192); \
        *(f32x4*)(outb + ((size_t)r * DDIM + cfl) * TT + (T0) + qfl * 4) = v; \
    }

    for (int t = 0; t < TT - 16; t += 16) {
        const unsigned short* gpt = g0 + (size_t)t * GXROW;
        SUBSTEP(0, true)  SUBSTEP(1, true)  SUBSTEP(2, true)  SUBSTEP(3, true)
        SUBSTEP(4, true)  SUBSTEP(5, true)  SUBSTEP(6, true)  SUBSTEP(7, true)
        SUBSTEP(8, true)  SUBSTEP(9, true)  SUBSTEP(10, true) SUBSTEP(11, true)
        SUBSTEP(12, true) SUBSTEP(13, true) SUBSTEP(14, true) SUBSTEP(15, true)
        FLUSH(t)
    }
    {
        const int t = TT - 16;
        const unsigned short* gpt = g0 + (size_t)t * GXROW;
        SUBSTEP(0, true)  SUBSTEP(1, true)  SUBSTEP(2, true)  SUBSTEP(3, true)
        SUBSTEP(4, true)  SUBSTEP(5, true)  SUBSTEP(6, true)  SUBSTEP(7, true)
        SUBSTEP(8, true)  SUBSTEP(9, true)  SUBSTEP(10, true) SUBSTEP(11, true)
        SUBSTEP(12, false) SUBSTEP(13, false) SUBSTEP(14, false) SUBSTEP(15, false)
        FLUSH(t)
    }
#undef GATE
#undef SUBSTEP
#undef FLUSH
}

// ---------------------------------------------------------------------------
// Fallback (round-1 kernel) if ws_size can't hold gx
// ---------------------------------------------------------------------------
typedef float f32x2 __attribute__((ext_vector_type(2)));

__global__ __launch_bounds__(768) void gru_fused(
    const float* __restrict__ x, const float* __restrict__ W,
    const float* __restrict__ U, const float* __restrict__ b,
    float* __restrict__ out)
{
    const int bb  = blockIdx.x;
    const int tid = threadIdx.x;
    const int kh  = (tid >= G3) ? 1 : 0;
    const int c   = tid - kh * G3;
    const int kbase = kh * 64;

    f32x2 wcol[32], ucol[32];
    #pragma unroll
    for (int k2 = 0; k2 < 32; ++k2) {
        wcol[k2][0] = W[(size_t)(kbase + 2*k2 + 0) * G3 + c];
        wcol[k2][1] = W[(size_t)(kbase + 2*k2 + 1) * G3 + c];
        ucol[k2][0] = U[(size_t)(kbase + 2*k2 + 0) * G3 + c];
        ucol[k2][1] = U[(size_t)(kbase + 2*k2 + 1) * G3 + c];
    }
    const float bias = b[c];

    __shared__ float xs[2][DDIM];
    __shared__ float hs[DDIM];
    __shared__ float px[G3], ph[G3];
    __shared__ float rs[DDIM], ns[DDIM];

    if (tid < DDIM) { hs[tid] = 0.0f; xs[0][tid] = x[((size_t)bb * DDIM + tid) * TT]; }
    __syncthreads();

    const float* __restrict__ xrow = x   + (size_t)bb * DDIM * TT;
    float* __restrict__       orow = out + (size_t)bb * DDIM * TT;
    float zv = 0.0f;

    for (int t = 0; t < TT; ++t) {
        const float* xcur = xs[t & 1] + kbase;
        const float* hcur = hs + kbase;
        f32x2 axv = {0.f, 0.f}, ahv = {0.f, 0.f};
        #pragma unroll
        for (int k2 = 0; k2 < 32; ++k2) {
            f32x2 xv = *(const f32x2*)(xcur + 2*k2);
            f32x2 hv = *(const f32x2*)(hcur + 2*k2);
            axv += xv * wcol[k2];
            ahv += hv * ucol[k2];
        }
        float ax = axv[0] + axv[1];
        float ah = ahv[0] + ahv[1];
        if (kh) { px[c] = ax; ph[c] = ah; }
        if (t + 1 < TT && tid >= 128 && tid < 256) {
            const int k = tid - 128;
            xs[(t + 1) & 1][k] = xrow[(size_t)k * TT + (t + 1)];
        }
        __syncthreads();
        if (!kh) {
            ax += px[c]; ah += ph[c];
            if (c < DDIM)            zv = sigm_(ax + ah + bias);
            else if (c < 2*DDIM)     rs[c - DDIM] = sigm_(ax + ah + bias);
            else { px[c] = ax + bias; ph[c] = ah; }
        }
        __syncthreads();
        if (!kh && c >= 2*DDIM) {
            float r = rs[c - 2*DDIM];
            ns[c - 2*DDIM] = tanhf_(px[c] + r * ph[c]);
        }
        __syncthreads();
        if (tid < DDIM) {
            float n = ns[tid];
            float hnew = zv * hs[tid] + (1.0f - zv) * n;
            hs[tid] = hnew;
            orow[(size_t)tid * TT + t] = hnew;
        }
        __syncthreads();
    }
}

extern "C" void kernel_launch(void* const* d_in, const int* in_sizes, int n_in,
                              void* d_out, int out_size, void* d_ws, size_t ws_size,
                              hipStream_t stream) {
    const float* x = (const float*)d_in[0];
    const float* W = (const float*)d_in[1];
    const float* U = (const float*)d_in[2];
    const float* b = (const float*)d_in[3];
    float* out     = (float*)d_out;

    if (ws_size >= GX_BYTES) {
        unsigned short* gx = (unsigned short*)d_ws;
        hipLaunchKernelGGL(gx_gemm, dim3(16, 16), dim3(256), 0, stream, x, W, b, gx);
        hipLaunchKernelGGL(gru_rec, dim3(16), dim3(512), 0, stream, gx, U, out);
    } else {
        hipLaunchKernelGGL(gru_fused, dim3(256), dim3(768), 0, stream, x, W, U, b, out);
    }
}

// Round 7
// 1675.907 us; speedup vs baseline: 2.7886x; 1.0723x over previous
//
#include <hip/hip_runtime.h>

typedef float f32x4 __attribute__((ext_vector_type(4)));
typedef short bf16x8 __attribute__((ext_vector_type(8)));

#define TT    2048
#define DDIM  128
#define G3    384
#define NBBLK 16
#define GXROW 6144   /* ushorts per t per batch-block: 24 tiles * 4 lk * 16 lc * 4 */
#define GX_BYTES ((size_t)NBBLK * TT * GXROW * 2)  /* 402,653,184 B */

// gate pre-scales: sigmoid(v) = rcp(1+exp2(-log2e * v)); tanh(u) = 2*rcp(1+exp2(-2log2e*u))-1
#define SCL_ZR (-1.4426950408889634f)
#define SCL_N  (-2.8853900817779268f)

__device__ __forceinline__ unsigned f2bf_u(float f) {
    unsigned u = __float_as_uint(f);
    return (u + 0x7FFFu + ((u >> 16) & 1u)) >> 16;   // RNE f32->bf16
}
__device__ __forceinline__ float bf_lo(unsigned u) { return __uint_as_float(u << 16); }
__device__ __forceinline__ float bf_hi(unsigned u) { return __uint_as_float(u & 0xffff0000u); }
__device__ __forceinline__ float rcp_(float x) { return __builtin_amdgcn_rcpf(x); }
__device__ __forceinline__ float exp2_(float x) {
    float d;
    asm("v_exp_f32 %0, %1" : "=v"(d) : "v"(x));   // register-only, safe
    return d;
}
__device__ __forceinline__ float sigm_(float v) { return rcp_(1.0f + exp2_(-1.4426950408889634f * v)); }
__device__ __forceinline__ float tanhf_(float v) { return 2.0f * rcp_(1.0f + exp2_(-2.8853900817779268f * v)) - 1.0f; }
__device__ __forceinline__ unsigned cvt_pk_bf16(float lo, float hi) {
    unsigned d;
    asm("v_cvt_pk_bf16_f32 %0, %1, %2" : "=v"(d) : "v"(lo), "v"(hi));
    return d;
}

// ---------------------------------------------------------------------------
// Kernel 1: gx^T = (x_t @ W + b)^T via swapped-operand MFMA (A = W^T frags).
// gx layout (ushort): [bblk][t][tile(24: 8z,8r,8n)][lk(4)][lc(16)][4]
//   lane (lc,lk) of consumer wave w reads its z/r/n uint2 at
//   ((g*8+w)*4+lk)*64 + lc*4 — 8B lane-stride, fully coalesced.
// Values pre-scaled by gate (SCL_ZR / SCL_N).
// ---------------------------------------------------------------------------
__global__ __launch_bounds__(256) void gx_gemm(
    const float* __restrict__ x, const float* __restrict__ W,
    const float* __restrict__ bias, unsigned short* __restrict__ gx)
{
    const int bblk  = blockIdx.x;
    const int ttile = blockIdx.y;
    const int tid = threadIdx.x;
    const int w  = tid >> 6;
    const int l  = tid & 63;
    const int lc = l & 15;
    const int lk = l >> 4;

    __shared__ unsigned short xs[16 * 16 * DDIM];   // [t16][r16][d128] bf16, swizzled

    const int tiles[6] = {2*w, 2*w+1, 2*w+8, 2*w+9, 2*w+16, 2*w+17};  // w in 0..3

    bf16x8 wfrag[6][4];      // A-operand: W^T fragments (pre-scaled)
    f32x4  binit[6];         // C-init: bias for the lane's 4 gate-cols (pre-scaled)
    #pragma unroll
    for (int i6 = 0; i6 < 6; ++i6) {
        const float scl = (i6 >= 4) ? SCL_N : SCL_ZR;
        #pragma unroll
        for (int i = 0; i < 4; ++i)
            binit[i6][i] = bias[tiles[i6] * 16 + lk * 4 + i] * scl;
        #pragma unroll
        for (int kt = 0; kt < 4; ++kt) {
            bf16x8 f;
            #pragma unroll
            for (int jj = 0; jj < 8; ++jj) {
                const int k = kt * 32 + lk * 8 + jj;
                f[jj] = (short)f2bf_u(W[k * G3 + tiles[i6] * 16 + lc] * scl);
            }
            wfrag[i6][kt] = f;
        }
    }

    int inoff[4];
    #pragma unroll
    for (int kt = 0; kt < 4; ++kt)
        inoff[kt] = (lc * 256 + kt * 64 + lk * 16) ^ ((lc & 7) << 4);

    const float* xb = x + (size_t)bblk * 16 * DDIM * TT;
    const int t0blk = ttile * 128;
    const int tq = tid & 3;
    const int pbase = tid >> 2;

    for (int chunk = 0; chunk < 8; ++chunk) {
        __syncthreads();
        const int t0 = t0blk + chunk * 16 + tq * 4;
        #pragma unroll 4
        for (int pp = 0; pp < 32; ++pp) {
            const int p = pbase + pp * 64;
            const int r = p >> 7, d = p & 127;
            f32x4 v = *(const f32x4*)(xb + (size_t)p * TT + t0);
            char* bp = (char*)xs + (tq * 4) * 4096 + (((r * 128 + d) * 2) ^ ((r & 7) << 4));
            const unsigned pkA = cvt_pk_bf16(v[0], v[1]);
            const unsigned pkB = cvt_pk_bf16(v[2], v[3]);
            *(unsigned short*)(bp)         = (unsigned short)pkA;
            *(unsigned short*)(bp + 4096)  = (unsigned short)(pkA >> 16);
            *(unsigned short*)(bp + 8192)  = (unsigned short)pkB;
            *(unsigned short*)(bp + 12288) = (unsigned short)(pkB >> 16);
        }
        __syncthreads();

        for (int t = 0; t < 16; ++t) {
            bf16x8 a[4];   // B-operand: x^T fragments (same lane data as before)
            #pragma unroll
            for (int kt = 0; kt < 4; ++kt)
                a[kt] = *(const bf16x8*)((const char*)xs + t * 4096 + inoff[kt]);

            const int tglob = t0blk + chunk * 16 + t;
            #pragma unroll
            for (int i6 = 0; i6 < 6; ++i6) {
                f32x4 acc = binit[i6];
                #pragma unroll
                for (int kt = 0; kt < 4; ++kt)
                    acc = __builtin_amdgcn_mfma_f32_16x16x32_bf16(wfrag[i6][kt], a[kt], acc, 0, 0, 0);
                unsigned p0 = cvt_pk_bf16(acc[0], acc[1]);   // gate-cols lk*4+0,1 of batch lc
                unsigned p1 = cvt_pk_bf16(acc[2], acc[3]);   // gate-cols lk*4+2,3
                const size_t off = (size_t)(bblk * TT + tglob) * GXROW
                                   + (size_t)(((tiles[i6] * 4 + lk) * 16 + lc) * 4);
                *(uint2*)(gx + off) = make_uint2(p0, p1);    // 8B lane-stride, coalesced
            }
        }
    }
}

// ---------------------------------------------------------------------------
// Kernel 2: sequential GRU recurrence, C^T (swapped-operand) form.
// 16 blocks x 512 threads (8 waves). Per step per wave: 4 ds_read_b128 (h),
// 1 ds_write_b64 (h bf16), 1 ds_write_b128 (out staging f32). Gates use
// pre-scaled exp2 + rcp only (no muls).
// ---------------------------------------------------------------------------
__global__ __launch_bounds__(512, 2) void gru_rec(
    const unsigned short* __restrict__ gx, const float* __restrict__ U,
    float* __restrict__ out)
{
    const int bblk = blockIdx.x;
    const int tid  = threadIdx.x;
    const int w  = tid >> 6;
    const int l  = tid & 63;
    const int lc = l & 15, lk = l >> 4;

    // A-operand: U^T fragments (identical lane data to old B-frags), pre-scaled
    bf16x8 uz[4], ur[4], un[4];
    #pragma unroll
    for (int kt = 0; kt < 4; ++kt) {
        bf16x8 fz, fr, fn;
        #pragma unroll
        for (int jj = 0; jj < 8; ++jj) {
            const int k = kt * 32 + lk * 8 + jj;
            fz[jj] = (short)f2bf_u(U[k * G3 + (w * 16 + lc)] * SCL_ZR);
            fr[jj] = (short)f2bf_u(U[k * G3 + 128 + (w * 16 + lc)] * SCL_ZR);
            fn[jj] = (short)f2bf_u(U[k * G3 + 256 + (w * 16 + lc)] * SCL_N);
        }
        uz[kt] = fz; ur[kt] = fr; un[kt] = fn;
    }

    __shared__ unsigned short hsA[2 * 2048];   // 8KB: 2 bufs x [batch16][d128] bf16, swizzled
    __shared__ float hlds[16 * 16 * 128];      // 128KB out staging [t16][b16][d128], swizzled
    #pragma unroll
    for (int i = tid; i < 4096; i += 512) hsA[i] = 0;
    char* const hb_lds = (char*)hlds;

    // B-frag (h) read byte-offsets: row=batch lc, 16B chunks along d
    int roff[4];
    #pragma unroll
    for (int kt = 0; kt < 4; ++kt)
        roff[kt] = lc * 256 + ((kt * 64 + lk * 16) ^ (lc << 4));

    // h write: single b64 at row lc, d-cols w*16+lk*4 .. +3
    const int wb64 = lc * 256 + ((w * 32 + lk * 8) ^ (lc << 4));

    // hlds write bases: row=batch lc, d-cols w*16+lk*4 (16B), xor (s=t>>2)<<6
    int hlv[4];
    {
        const int hlbase = lc * 512 + ((w * 64 + lk * 16) ^ ((lc & 7) << 4));
        #pragma unroll
        for (int s = 0; s < 4; ++s) hlv[s] = hlbase ^ (s << 6);
    }

    // flush: lane covers (d = dl, t-quad qfl); round r covers batch b = r
    const int dl  = w * 16 + (l >> 2);
    const int qfl = l & 3;
    const int flb = qfl * 32768 + ((dl * 4) ^ (qfl << 6));
    float* outl = out + ((size_t)bblk * 16 * DDIM + dl) * TT + qfl * 4;

    float hold[4] = {0.f, 0.f, 0.f, 0.f};

    const unsigned short* g0 = gx + (size_t)bblk * TT * GXROW
                               + (size_t)(((w * 4 + lk) * 16 + lc) * 4);

    // depth-4 gx prefetch ring (z at +0, r at +2048, n at +4096 ushorts)
    uint2 rgz[4], rgr[4], rgn[4];
    #pragma unroll
    for (int d = 0; d < 4; ++d) {
        const unsigned short* gq = g0 + (size_t)d * GXROW;
        rgz[d] = *(const uint2*)(gq);
        rgr[d] = *(const uint2*)(gq + 2048);
        rgn[d] = *(const uint2*)(gq + 4096);
    }

    __syncthreads();

#define GATE(I)                                                               \
    {                                                                         \
        const float zz = rcp_(1.0f + exp2_(az_a[I] + az_b[I]));               \
        const float rr = rcp_(1.0f + exp2_(ar_a[I] + ar_b[I]));               \
        const float uu = gn##I + rr * (an_a[I] + an_b[I]);                    \
        const float nn = 2.0f * rcp_(1.0f + exp2_(uu)) - 1.0f;                \
        const float hn = nn + zz * (hold[I] - nn);                            \
        hold[I] = hn;                                                         \
        hh[I] = hn;                                                           \
    }

#define SUBSTEP(J, DOPF)                                                      \
    {                                                                         \
        const char* hb = (const char*)hsA + ((J) & 1) * 4096;                 \
        bf16x8 b0 = *(const bf16x8*)(hb + roff[0]);                           \
        bf16x8 b1 = *(const bf16x8*)(hb + roff[1]);                           \
        bf16x8 b2 = *(const bf16x8*)(hb + roff[2]);                           \
        bf16x8 b3 = *(const bf16x8*)(hb + roff[3]);                           \
        uint2 pz = rgz[(J) & 3], pr = rgr[(J) & 3], pn = rgn[(J) & 3];        \
        if (DOPF) {                                                           \
            const unsigned short* gq = gpt + (size_t)((J) + 4) * GXROW;       \
            rgz[(J) & 3] = *(const uint2*)(gq);                               \
            rgr[(J) & 3] = *(const uint2*)(gq + 2048);                        \
            rgn[(J) & 3] = *(const uint2*)(gq + 4096);                        \
        }                                                                     \
        f32x4 az_a, ar_a;                                                     \
        az_a[0] = bf_lo(pz.x); az_a[1] = bf_hi(pz.x);                         \
        az_a[2] = bf_lo(pz.y); az_a[3] = bf_hi(pz.y);                         \
        ar_a[0] = bf_lo(pr.x); ar_a[1] = bf_hi(pr.x);                         \
        ar_a[2] = bf_lo(pr.y); ar_a[3] = bf_hi(pr.y);                         \
        const float gn0 = bf_lo(pn.x), gn1 = bf_hi(pn.x);                     \
        const float gn2 = bf_lo(pn.y), gn3 = bf_hi(pn.y);                     \
        f32x4 an_a = (f32x4){0.f, 0.f, 0.f, 0.f};                             \
        f32x4 an_b = an_a, az_b = an_a, ar_b = an_a;                          \
        an_a = __builtin_amdgcn_mfma_f32_16x16x32_bf16(un[0], b0, an_a, 0, 0, 0); \
        an_b = __builtin_amdgcn_mfma_f32_16x16x32_bf16(un[2], b2, an_b, 0, 0, 0); \
        az_a = __builtin_amdgcn_mfma_f32_16x16x32_bf16(uz[0], b0, az_a, 0, 0, 0); \
        az_b = __builtin_amdgcn_mfma_f32_16x16x32_bf16(uz[2], b2, az_b, 0, 0, 0); \
        ar_a = __builtin_amdgcn_mfma_f32_16x16x32_bf16(ur[0], b0, ar_a, 0, 0, 0); \
        ar_b = __builtin_amdgcn_mfma_f32_16x16x32_bf16(ur[2], b2, ar_b, 0, 0, 0); \
        an_a = __builtin_amdgcn_mfma_f32_16x16x32_bf16(un[1], b1, an_a, 0, 0, 0); \
        an_b = __builtin_amdgcn_mfma_f32_16x16x32_bf16(un[3], b3, an_b, 0, 0, 0); \
        az_a = __builtin_amdgcn_mfma_f32_16x16x32_bf16(uz[1], b1, az_a, 0, 0, 0); \
        az_b = __builtin_amdgcn_mfma_f32_16x16x32_bf16(uz[3], b3, az_b, 0, 0, 0); \
        ar_a = __builtin_amdgcn_mfma_f32_16x16x32_bf16(ur[1], b1, ar_a, 0, 0, 0); \
        ar_b = __builtin_amdgcn_mfma_f32_16x16x32_bf16(ur[3], b3, ar_b, 0, 0, 0); \
        float hh[4];                                                          \
        GATE(0) GATE(1) GATE(2) GATE(3)                                       \
        {                                                                     \
            const unsigned pk01 = cvt_pk_bf16(hh[0], hh[1]);                  \
            const unsigned pk23 = cvt_pk_bf16(hh[2], hh[3]);                  \
            *(uint2*)((char*)hsA + ((((J) & 1) ^ 1) * 4096) + wb64)           \
                = make_uint2(pk01, pk23);                                     \
        }                                                                     \
        *(f32x4*)(hb_lds + hlv[(J) >> 2] + (J) * 8192)                        \
            = (f32x4){hh[0], hh[1], hh[2], hh[3]};                            \
        asm volatile("s_waitcnt lgkmcnt(0)" ::: "memory");                    \
        __builtin_amdgcn_s_barrier();                                         \
    }

    // flush: own-wave data only -> no barrier needed
#define FLUSH(T0)                                                             \
    _Pragma("unroll")                                                         \
    for (int r = 0; r < 16; ++r) {                                            \
        const int fr = (flb ^ ((r & 7) << 4)) + r * 512;                      \
        f32x4 v;                                                              \
        _Pragma("unroll")                                                     \
        for (int k = 0; k < 4; ++k)                                           \
            v[k] = *(const float*)(hb_lds + fr + k * 8192);                   \
        *(f32x4*)(outl + (size_t)r * (DDIM * TT) + (T0)) = v;                 \
    }

    for (int t = 0; t < TT - 16; t += 16) {
        const unsigned short* gpt = g0 + (size_t)t * GXROW;
        SUBSTEP(0, true)  SUBSTEP(1, true)  SUBSTEP(2, true)  SUBSTEP(3, true)
        SUBSTEP(4, true)  SUBSTEP(5, true)  SUBSTEP(6, true)  SUBSTEP(7, true)
        SUBSTEP(8, true)  SUBSTEP(9, true)  SUBSTEP(10, true) SUBSTEP(11, true)
        SUBSTEP(12, true) SUBSTEP(13, true) SUBSTEP(14, true) SUBSTEP(15, true)
        FLUSH(t)
    }
    {
        const int t = TT - 16;
        const unsigned short* gpt = g0 + (size_t)t * GXROW;
        SUBSTEP(0, true)  SUBSTEP(1, true)  SUBSTEP(2, true)  SUBSTEP(3, true)
        SUBSTEP(4, true)  SUBSTEP(5, true)  SUBSTEP(6, true)  SUBSTEP(7, true)
        SUBSTEP(8, true)  SUBSTEP(9, true)  SUBSTEP(10, true) SUBSTEP(11, true)
        SUBSTEP(12, false) SUBSTEP(13, false) SUBSTEP(14, false) SUBSTEP(15, false)
        FLUSH(t)
    }
#undef GATE
#undef SUBSTEP
#undef FLUSH
}

// ---------------------------------------------------------------------------
// Fallback (round-1 kernel) if ws_size can't hold gx
// ---------------------------------------------------------------------------
typedef float f32x2 __attribute__((ext_vector_type(2)));

__global__ __launch_bounds__(768) void gru_fused(
    const float* __restrict__ x, const float* __restrict__ W,
    const float* __restrict__ U, const float* __restrict__ b,
    float* __restrict__ out)
{
    const int bb  = blockIdx.x;
    const int tid = threadIdx.x;
    const int kh  = (tid >= G3) ? 1 : 0;
    const int c   = tid - kh * G3;
    const int kbase = kh * 64;

    f32x2 wcol[32], ucol[32];
    #pragma unroll
    for (int k2 = 0; k2 < 32; ++k2) {
        wcol[k2][0] = W[(size_t)(kbase + 2*k2 + 0) * G3 + c];
        wcol[k2][1] = W[(size_t)(kbase + 2*k2 + 1) * G3 + c];
        ucol[k2][0] = U[(size_t)(kbase + 2*k2 + 0) * G3 + c];
        ucol[k2][1] = U[(size_t)(kbase + 2*k2 + 1) * G3 + c];
    }
    const float bias = b[c];

    __shared__ float xs[2][DDIM];
    __shared__ float hs[DDIM];
    __shared__ float px[G3], ph[G3];
    __shared__ float rs[DDIM], ns[DDIM];

    if (tid < DDIM) { hs[tid] = 0.0f; xs[0][tid] = x[((size_t)bb * DDIM + tid) * TT]; }
    __syncthreads();

    const float* __restrict__ xrow = x   + (size_t)bb * DDIM * TT;
    float* __restrict__       orow = out + (size_t)bb * DDIM * TT;
    float zv = 0.0f;

    for (int t = 0; t < TT; ++t) {
        const float* xcur = xs[t & 1] + kbase;
        const float* hcur = hs + kbase;
        f32x2 axv = {0.f, 0.f}, ahv = {0.f, 0.f};
        #pragma unroll
        for (int k2 = 0; k2 < 32; ++k2) {
            f32x2 xv = *(const f32x2*)(xcur + 2*k2);
            f32x2 hv = *(const f32x2*)(hcur + 2*k2);
            axv += xv * wcol[k2];
            ahv += hv * ucol[k2];
        }
        float ax = axv[0] + axv[1];
        float ah = ahv[0] + ahv[1];
        if (kh) { px[c] = ax; ph[c] = ah; }
        if (t + 1 < TT && tid >= 128 && tid < 256) {
            const int k = tid - 128;
            xs[(t + 1) & 1][k] = xrow[(size_t)k * TT + (t + 1)];
        }
        __syncthreads();
        if (!kh) {
            ax += px[c]; ah += ph[c];
            if (c < DDIM)            zv = sigm_(ax + ah + bias);
            else if (c < 2*DDIM)     rs[c - DDIM] = sigm_(ax + ah + bias);
            else { px[c] = ax + bias; ph[c] = ah; }
        }
        __syncthreads();
        if (!kh && c >= 2*DDIM) {
            float r = rs[c - 2*DDIM];
            ns[c - 2*DDIM] = tanhf_(px[c] + r * ph[c]);
        }
        __syncthreads();
        if (tid < DDIM) {
            float n = ns[tid];
            float hnew = zv * hs[tid] + (1.0f - zv) * n;
            hs[tid] = hnew;
            orow[(size_t)tid * TT + t] = hnew;
        }
        __syncthreads();
    }
}

extern "C" void kernel_launch(void* const* d_in, const int* in_sizes, int n_in,
                              void* d_out, int out_size, void* d_ws, size_t ws_size,
                              hipStream_t stream) {
    const float* x = (const float*)d_in[0];
    const float* W = (const float*)d_in[1];
    const float* U = (const float*)d_in[2];
    const float* b = (const float*)d_in[3];
    float* out     = (float*)d_out;

    if (ws_size >= GX_BYTES) {
        unsigned short* gx = (unsigned short*)d_ws;
        hipLaunchKernelGGL(gx_gemm, dim3(16, 16), dim3(256), 0, stream, x, W, b, gx);
        hipLaunchKernelGGL(gru_rec, dim3(16), dim3(512), 0, stream, gx, U, out);
    } else {
        hipLaunchKernelGGL(gru_fused, dim3(256), dim3(768), 0, stream, x, W, U, b, out);
    }
}